// Round 2
// baseline (4846.178 us; speedup 1.0000x reference)
//
#include <hip/hip_runtime.h>

// ---------------------------------------------------------------------------
// VanillaRNN on MI355X.  B=64, T=512, I=512, H=1024, C=1000.
//
// Phase 1: xh = x @ Wx^T + bx  (parallel MFMA GEMM) written TRANSPOSED as
//          xh_T[n][m] (n=hidden col, m=b*512+t), bf16 (unchanged, proven).
// Phase 2: ring of 4 groups x 64 waves with SELF-TESTED scope:
//   - roster claim: wave reads HW_REG_XCC_ID (m09-verified); first 64
//     claimers on XCDs 0-3 become ring g=xcc (slot=w); others exit.
//   - bounded sc0 handshake verifies all 64 ring-mates are mutually visible
//     through the XCD's L2.  Verdicts exchanged at agent scope (always
//     correct).  Unanimous OK -> L2 mode (sc0 ops, ~250cy RT); otherwise
//     -> L3 mode (sc1 ops == the proven agent-atomic semantics, ~1.1k RT).
//     Wrong sc0 semantics or wrong XCC_ID degrade to L3, never hang.
//   - per step: ONE fused poll (lane i polls flag i, own skipped) ->
//     h loads in 4 counted-vmcnt banks of 8 x dwordx4 (2 banks in flight,
//     peak 64 VGPR; bank k+1's RT hides under MFMA of bank k) -> 32 MFMA
//     on 4 acc chains -> tanh -> LDS transpose -> one 8-B store ->
//     vmcnt(0) -> flag store.  sched_barrier(0) after every manual wait
//     (rule #18).
//   - h ring depth 4; single poll of flags>=t-1 before reading slot t-2
//     keeps the reuse-safety argument of the original kernel.
//   - flags/roster/handshake state ZEROED by init_k each launch.
// Phase 3: fp32 logits GEMV (reads ring slot 3 == h[T]).
// ---------------------------------------------------------------------------

typedef __bf16 bf16x8 __attribute__((ext_vector_type(8)));
typedef float  f32x4  __attribute__((ext_vector_type(4)));
typedef int    i32x4  __attribute__((ext_vector_type(4)));
typedef unsigned long long u64;
typedef unsigned short u16;

#define B_SZ 64
#define T_SZ 512
#define IDIM 512
#define HDIM 1024
#define NCLS 1000
#define MTOT (B_SZ * T_SZ)   // 32768

template <bool V> struct BoolC { static constexpr bool value = V; };

__device__ __forceinline__ float tanh_fast(float v) {
    float e = __builtin_amdgcn_exp2f(v * 2.885390081777927f);
    return 1.f - 2.f * __builtin_amdgcn_rcpf(e + 1.f);
}

__device__ __forceinline__ bf16x8 cvt8(float4 a, float4 b) {
    bf16x8 v;
    v[0]=(__bf16)a.x; v[1]=(__bf16)a.y; v[2]=(__bf16)a.z; v[3]=(__bf16)a.w;
    v[4]=(__bf16)b.x; v[5]=(__bf16)b.y; v[6]=(__bf16)b.z; v[7]=(__bf16)b.w;
    return v;
}

__device__ __forceinline__ f32x4 mfma_hb(i32x4 a, bf16x8 b, f32x4 c) {
    return __builtin_amdgcn_mfma_f32_16x16x32_bf16(__builtin_bit_cast(bf16x8, a), b, c, 0, 0, 0);
}

// MFMA 16x16x32 bf16 layouts (m89/m91 verified):
//   A[m = lane&15][k = (lane>>4)*8 + j]
//   B[k = (lane>>4)*8 + j][n = lane&15]
//   D[row = (lane>>4)*4 + r][col = lane&15]

// ---------------------------------------------------------------------------
// Phase 1: xh GEMM with transposed output (unchanged, proven).
// ---------------------------------------------------------------------------
__global__ __launch_bounds__(256)
void xh_gemm(const float* __restrict__ x,    // (32768, 512)
             const float* __restrict__ Wx,   // (1024, 512)
             const float* __restrict__ bx,   // (1024)
             __bf16* __restrict__ xh_T)      // (1024, 32768) bf16
{
    __shared__ __attribute__((aligned(16))) u16 tile_sh[64 * 72];  // [n][m], stride 72

    const int m0   = (blockIdx.x >> 4) * 64;
    const int n0   = (blockIdx.x & 15) * 64;
    const int wv   = threadIdx.x >> 6;
    const int lane = threadIdx.x & 63;
    const int l15  = lane & 15;
    const int quad = lane >> 4;
    const int nabs = n0 + wv * 16 + l15;

    bf16x8 wxf[16];
#pragma unroll
    for (int kk = 0; kk < 16; ++kk) {
        const float4* p = (const float4*)(Wx + (size_t)nabs * IDIM + kk * 32 + quad * 8);
        wxf[kk] = cvt8(p[0], p[1]);
    }
    const float bxv = bx[nabs];

    f32x4 acc[4] = {{0,0,0,0},{0,0,0,0},{0,0,0,0},{0,0,0,0}};
#pragma unroll
    for (int kk = 0; kk < 16; ++kk) {
#pragma unroll
        for (int rf = 0; rf < 4; ++rf) {
            const float4* p = (const float4*)(x + (size_t)(m0 + rf * 16 + l15) * IDIM + kk * 32 + quad * 8);
            bf16x8 a = cvt8(p[0], p[1]);
            acc[rf] = __builtin_amdgcn_mfma_f32_16x16x32_bf16(a, wxf[kk], acc[rf], 0, 0, 0);
        }
    }
#pragma unroll
    for (int rf = 0; rf < 4; ++rf)
#pragma unroll
        for (int r = 0; r < 4; ++r) {
            __bf16 hv = (__bf16)(acc[rf][r] + bxv);
            tile_sh[(wv * 16 + l15) * 72 + rf * 16 + quad * 4 + r] =
                __builtin_bit_cast(u16, hv);
        }
    __syncthreads();
#pragma unroll
    for (int rep = 0; rep < 2; ++rep) {
        const int nl  = (threadIdx.x >> 3) + rep * 32;
        const int mch = threadIdx.x & 7;
        uint4 v;
        __builtin_memcpy(&v, &tile_sh[nl * 72 + mch * 8], 16);
        *(uint4*)(xh_T + (size_t)(n0 + nl) * MTOT + m0 + mch * 8) = v;
    }
}

// ---------------------------------------------------------------------------
// init: zero all sync state (flags, roster, handshake, verdicts).
// sync layout (ints): flags[4][64] @0, roster[8] @256, hs[4][64] @320,
//                     vd[4][64] @576.  1024 ints total.
// ---------------------------------------------------------------------------
__global__ __launch_bounds__(256)
void init_k(int* sync) {
#pragma unroll
    for (int i = 0; i < 4; ++i) sync[threadIdx.x + i * 256] = 0;
}

// --------- scope-dependent memory ops (L3 == proven agent semantics) -------
#define SB0 __builtin_amdgcn_sched_barrier(0)

#define PLOAD(dst) do { if constexpr (L3) \
    asm volatile("global_load_dword %0, %1, off sc1\n\ts_waitcnt vmcnt(0)" : "=v"(dst) : "v"(pollp) : "memory"); \
  else \
    asm volatile("global_load_dword %0, %1, off sc0\n\ts_waitcnt vmcnt(0)" : "=v"(dst) : "v"(pollp) : "memory"); } while(0)

#define LDH(arr, n, off) do { if constexpr (L3) \
    asm volatile("global_load_dwordx4 %0, %1, off offset:" #off " sc1" : "=v"(arr[n]) : "v"(hq) : "memory"); \
  else \
    asm volatile("global_load_dwordx4 %0, %1, off offset:" #off " sc0" : "=v"(arr[n]) : "v"(hq) : "memory"); } while(0)

#define LDB0(a) do { LDH(a,0,0);    LDH(a,1,64);   LDH(a,2,128);  LDH(a,3,192);  \
                     LDH(a,4,256);  LDH(a,5,320);  LDH(a,6,384);  LDH(a,7,448);  } while(0)
#define LDB1(a) do { LDH(a,0,512);  LDH(a,1,576);  LDH(a,2,640);  LDH(a,3,704);  \
                     LDH(a,4,768);  LDH(a,5,832);  LDH(a,6,896);  LDH(a,7,960);  } while(0)
#define LDB2(a) do { LDH(a,0,1024); LDH(a,1,1088); LDH(a,2,1152); LDH(a,3,1216); \
                     LDH(a,4,1280); LDH(a,5,1344); LDH(a,6,1408); LDH(a,7,1472); } while(0)
#define LDB3(a) do { LDH(a,0,1536); LDH(a,1,1600); LDH(a,2,1664); LDH(a,3,1728); \
                     LDH(a,4,1792); LDH(a,5,1856); LDH(a,6,1920); LDH(a,7,1984); } while(0)

#define WAIT8 do { asm volatile("s_waitcnt vmcnt(8)" ::: "memory"); SB0; } while(0)
#define WAIT0 do { asm volatile("s_waitcnt vmcnt(0)" ::: "memory"); SB0; } while(0)

#define MFB(arr, wb) do { \
    acc0 = mfma_hb(arr[0], whf[wb+0], acc0); acc1 = mfma_hb(arr[1], whf[wb+1], acc1); \
    acc2 = mfma_hb(arr[2], whf[wb+2], acc2); acc3 = mfma_hb(arr[3], whf[wb+3], acc3); \
    acc0 = mfma_hb(arr[4], whf[wb+4], acc0); acc1 = mfma_hb(arr[5], whf[wb+5], acc1); \
    acc2 = mfma_hb(arr[6], whf[wb+6], acc2); acc3 = mfma_hb(arr[7], whf[wb+7], acc3); } while(0)

#define HSTORE(d, v) do { if constexpr (L3) \
    asm volatile("global_store_dwordx2 %0, %1, off sc1" :: "v"(d), "v"(v) : "memory"); \
  else \
    asm volatile("global_store_dwordx2 %0, %1, off sc0" :: "v"(d), "v"(v) : "memory"); } while(0)

#define FSTORE(d, v) do { if constexpr (L3) \
    asm volatile("global_store_dword %0, %1, off sc1" :: "v"(d), "v"(v) : "memory"); \
  else \
    asm volatile("global_store_dword %0, %1, off sc0" :: "v"(d), "v"(v) : "memory"); } while(0)

// ---------------------------------------------------------------------------
// Phase 2: the scope-adaptive ring.
//   h_ring layout: [ring g][slot 0..3][row 0..15][col 0..1023] bf16.
// ---------------------------------------------------------------------------
template <bool HAS_XH>
__global__ __launch_bounds__(64, 1)
void rnn_ring(const float* __restrict__ x,    // (64,512,512)
              const float* __restrict__ Wx,   // (1024,512)
              const float* __restrict__ bx,   // (1024)
              const float* __restrict__ Wh,   // (1024,1024)
              const __bf16* __restrict__ xh,  // (1024,32768) bf16 xh_T (HAS_XH)
              __bf16* h_ring,                 // (4,4,16,1024) bf16, ws
              int* sync)                      // 1024 ints, ws
{
    __shared__ __attribute__((aligned(16))) u16 xh_sh[64 * 68];  // per-lane xh stash
    __shared__ __attribute__((aligned(16))) u16 ep_sh[16 * 20];  // epilogue transpose

    const int lane = threadIdx.x;

    // ---- XCD roster claim ---------------------------------------------------
    unsigned xcc;
    asm volatile("s_getreg_b32 %0, hwreg(HW_REG_XCC_ID)" : "=s"(xcc));
    xcc &= 7u;
    int slot = 0;
    if (lane == 0)
        slot = __hip_atomic_fetch_add(sync + 256 + (int)xcc, 1,
                                      __ATOMIC_RELAXED, __HIP_MEMORY_SCOPE_AGENT);
    slot = __shfl(slot, 0);
    if (xcc >= 4u || slot >= 64) return;    // non-worker: exit

    const int g    = (int)xcc;
    const int w    = slot;
    const int l15  = lane & 15;
    const int quad = lane >> 4;
    const int nabs = w * 16 + l15;

    bf16x8 whf[32];
#pragma unroll
    for (int kk = 0; kk < 32; ++kk) {
        const float4* p = (const float4*)(Wh + (size_t)nabs * HDIM + kk * 32 + quad * 8);
        whf[kk] = cvt8(p[0], p[1]);
    }
    bf16x8 wxf[16];
    float bxv = 0.f;
    if (!HAS_XH) {
#pragma unroll
        for (int kk = 0; kk < 16; ++kk) {
            const float4* p = (const float4*)(Wx + (size_t)nabs * IDIM + kk * 32 + quad * 8);
            wxf[kk] = cvt8(p[0], p[1]);
        }
        bxv = bx[nabs];
    }

    int* fl     = sync + g * 64;
    int* myflag = fl + w;
    int* pollp  = fl + lane;
    __bf16* ring = h_ring + (size_t)g * (4 * 16 * HDIM);
    const float* xrow = x + (size_t)(g * 16 + l15) * T_SZ * IDIM + quad * 8;
    const int prow = lane >> 2;
    const int pcg  = lane & 3;

    // ---- bounded L2 handshake; verdict exchange at agent scope -------------
    {
        int* hsme = sync + 320 + g * 64 + w;
        int* hsp  = sync + 320 + g * 64 + lane;
        if (lane == 0)
            asm volatile("global_store_dword %0, %1, off sc0" :: "v"(hsme), "v"(1) : "memory");
        asm volatile("s_waitcnt vmcnt(0)" ::: "memory");
        int ok = 0;
        for (int it = 0; it < 10000 && !ok; ++it) {
            int hv_;
            asm volatile("global_load_dword %0, %1, off sc0\n\ts_waitcnt vmcnt(0)"
                         : "=v"(hv_) : "v"(hsp) : "memory");
            ok = __all(hv_ == 1);
        }
        if (lane == 0)
            __hip_atomic_store(sync + 576 + g * 64 + w, ok ? 1 : 2,
                               __ATOMIC_RELAXED, __HIP_MEMORY_SCOPE_AGENT);
    }
    int l3mode;
    {
        const int* vdp = sync + 576 + g * 64 + lane;
        for (;;) {
            int vv = __hip_atomic_load(vdp, __ATOMIC_RELAXED, __HIP_MEMORY_SCOPE_AGENT);
            if (__all(vv != 0)) { l3mode = __any(vv == 2); break; }
        }
    }

    // ---- main recurrence (instantiated for both scopes) ---------------------
    auto run = [&](auto l3c) {
        constexpr bool L3 = decltype(l3c)::value;

        for (int t = 1; t <= T_SZ; ++t) {
            f32x4 acc0 = {0.f,0.f,0.f,0.f};
            f32x4 acc1 = {0.f,0.f,0.f,0.f};
            f32x4 acc2 = {0.f,0.f,0.f,0.f};
            f32x4 acc3 = {0.f,0.f,0.f,0.f};
            float xhv[4];

            if (HAS_XH) {
                if (((t - 1) & 15) == 0) {
                    const int tb = t - 1;
#pragma unroll
                    for (int r = 0; r < 4; ++r) {
                        const int row = g * 16 + quad * 4 + r;
                        const uint4* xp = (const uint4*)(xh + (size_t)nabs * MTOT + row * T_SZ + tb);
                        uint4 v0 = xp[0], v1 = xp[1];
                        __builtin_memcpy(&xh_sh[lane * 68 + r * 16],     &v0, 16);
                        __builtin_memcpy(&xh_sh[lane * 68 + r * 16 + 8], &v1, 16);
                    }
                }
                const int p = (t - 1) & 15;
#pragma unroll
                for (int r = 0; r < 4; ++r) {
                    u16 us = xh_sh[lane * 68 + r * 16 + p];
                    xhv[r] = (float)__builtin_bit_cast(__bf16, us);
                }
            } else {
                const float4* xp = (const float4*)(xrow + (size_t)(t - 1) * IDIM);
#pragma unroll
                for (int kk = 0; kk < 16; kk += 2) {
                    bf16x8 v0 = cvt8(xp[kk * 8], xp[kk * 8 + 1]);
                    acc0 = __builtin_amdgcn_mfma_f32_16x16x32_bf16(v0, wxf[kk], acc0, 0, 0, 0);
                    bf16x8 v1 = cvt8(xp[kk * 8 + 8], xp[kk * 8 + 9]);
                    acc1 = __builtin_amdgcn_mfma_f32_16x16x32_bf16(v1, wxf[kk + 1], acc1, 0, 0, 0);
                }
#pragma unroll
                for (int r = 0; r < 4; ++r) xhv[r] = bxv;
            }

            if (t > 1) {
                // ---- ONE fused poll: lane i polls flag i (own skipped) -----
                int fv;
                do { PLOAD(fv); } while (!__all((lane == w) | (fv >= t - 1)));
                SB0;

                // ---- h loads: 4 banks of 8, 2 in flight, counted vmcnt -----
                const __bf16* hq = ring + (size_t)(((t - 2) & 3) * 16 + l15) * HDIM + quad * 8;
                i32x4 hA[8], hB[8];
                LDB0(hA);
                LDB1(hB);
                WAIT8;            // bank0 landed (bank1 in flight)
                MFB(hA, 0);
                LDB2(hA);         // reuse bank-A regs (anti-dep keeps order)
                WAIT8;            // bank1 landed (bank2 in flight)
                MFB(hB, 8);
                LDB3(hB);
                WAIT8;            // bank2 landed (bank3 in flight)
                MFB(hA, 16);
                WAIT0;            // bank3 landed
                MFB(hB, 24);
            }

            // ---- epilogue: tanh -> LDS transpose -> one 8-B store ----------
#pragma unroll
            for (int r = 0; r < 4; ++r) {
                float a = acc0[r] + acc1[r] + acc2[r] + acc3[r] + xhv[r];
                __bf16 hb = (__bf16)tanh_fast(a);
                ep_sh[(quad * 4 + r) * 20 + l15] = __builtin_bit_cast(u16, hb);
            }
            u64 pv;
            __builtin_memcpy(&pv, &ep_sh[prow * 20 + pcg * 4], 8);  // same-wave
            __bf16* dst = ring + (size_t)(((t - 1) & 3) * 16 + prow) * HDIM + w * 16 + pcg * 4;
            HSTORE(dst, pv);

            // ---- publish: drain data store, then flag ----------------------
            WAIT0;
            if (lane == 0) FSTORE(myflag, t);
        }
    };

    if (l3mode) run(BoolC<true>{});
    else        run(BoolC<false>{});
}

// ---------------------------------------------------------------------------
// Phase 3: logits[b][j] = sum_k hT[b][k] * Wy[j][k] + by[j]   (fp32)
//   hT row b lives at ring (b>>4), slot 3 (= (T-1)&3), local row (b&15).
// ---------------------------------------------------------------------------
__global__ __launch_bounds__(256)
void logits_k(const __bf16* __restrict__ h_ring, // (4,4,16,1024) bf16
              const float* __restrict__ Wy,      // (1000,1024)
              const float* __restrict__ by,      // (1000)
              float* __restrict__ out)           // (64,1000)
{
    const int j = blockIdx.x;
    const int q = threadIdx.x & 3;
    const int b = threadIdx.x >> 2;
    const float*  wr = Wy + (size_t)j * HDIM + q * 256;
    const __bf16* hr = h_ring + ((size_t)((b >> 4) * 4 + 3) * 16 + (b & 15)) * HDIM + q * 256;
    float s = 0.f;
#pragma unroll 8
    for (int kk = 0; kk < 32; ++kk) {
        bf16x8 h8 = *(const bf16x8*)(hr + kk * 8);
        float4 w0 = *(const float4*)(wr + kk * 8);
        float4 w1 = *(const float4*)(wr + kk * 8 + 4);
        s += w0.x * (float)h8[0] + w0.y * (float)h8[1] + w0.z * (float)h8[2] + w0.w * (float)h8[3]
           + w1.x * (float)h8[4] + w1.y * (float)h8[5] + w1.z * (float)h8[6] + w1.w * (float)h8[7];
    }
    s += __shfl_xor(s, 1);
    s += __shfl_xor(s, 2);
    if (q == 0) out[b * NCLS + j] = s + by[j];
}

extern "C" void kernel_launch(void* const* d_in, const int* in_sizes, int n_in,
                              void* d_out, int out_size, void* d_ws, size_t ws_size,
                              hipStream_t stream) {
    (void)in_sizes; (void)n_in; (void)out_size;
    const float* x  = (const float*)d_in[0];
    const float* Wx = (const float*)d_in[1];
    const float* bx = (const float*)d_in[2];
    const float* Wh = (const float*)d_in[3];
    const float* Wy = (const float*)d_in[4];
    const float* by = (const float*)d_in[5];

    const size_t xh_bytes    = (size_t)MTOT * HDIM * 2;              // 67.1 MB
    const size_t hring_bytes = (size_t)4 * 4 * 16 * HDIM * 2;        // 512 KB
    const size_t sync_bytes  = 1024 * sizeof(int);                   // 4 KB
    const bool   big_ws      = ws_size >= xh_bytes + hring_bytes + sync_bytes + 4096;

    if (big_ws) {
        __bf16* xh_T   = (__bf16*)d_ws;
        __bf16* h_ring = (__bf16*)((char*)d_ws + xh_bytes);
        int*    sync   = (int*)((char*)d_ws + xh_bytes + hring_bytes);
        xh_gemm<<<dim3(8192), dim3(256), 0, stream>>>(x, Wx, bx, xh_T);
        init_k<<<dim3(1), dim3(256), 0, stream>>>(sync);
        rnn_ring<true><<<dim3(1024), dim3(64), 0, stream>>>(x, Wx, bx, Wh, xh_T, h_ring, sync);
        logits_k<<<dim3(NCLS), dim3(256), 0, stream>>>(h_ring, Wy, by, (float*)d_out);
    } else {
        __bf16* h_ring = (__bf16*)d_ws;
        int*    sync   = (int*)((char*)d_ws + hring_bytes);
        init_k<<<dim3(1), dim3(256), 0, stream>>>(sync);
        rnn_ring<false><<<dim3(1024), dim3(64), 0, stream>>>(x, Wx, bx, Wh, nullptr, h_ring, sync);
        logits_k<<<dim3(NCLS), dim3(256), 0, stream>>>(h_ring, Wy, by, (float*)d_out);
    }
}

// Round 3
// 2326.946 us; speedup vs baseline: 2.0826x; 2.0826x over previous
//
#include <hip/hip_runtime.h>

// ---------------------------------------------------------------------------
// VanillaRNN on MI355X.  B=64, T=512, I=512, H=1024, C=1000.
//
// Phase 1: xh = x @ Wx^T + bx  (parallel MFMA GEMM) written TRANSPOSED as
//          xh_T[n][m] (n=hidden col, m=b*512+t), bf16 (unchanged, proven).
// Phase 2: cooperative-WG ring.  4 rings (batch groups of 16 rows) x
//   8 workgroups x 8 waves (512 thr).  WG v owns output cols v*128..+127
//   (wave u: cols v*128+u*16..+15).  Wh B-frags register-resident (128 VGPR).
//   Per step:
//     - poll 8 per-WG flags (ONE L3 line) at agent scope (sc0 sc1 -- the
//       proven encoding from the 3.15ms kernel; round-2 showed sc0-only
//       polls stall on stale L1);
//     - 8 waves COOPERATIVELY load the 32KB h(t-1) once (4KB/wave,
//       4 x dwordx4 sc0 sc1) -> 8x less L3 traffic than per-wave loads;
//     - stage into LDS in A-frag-major XOR-swizzled layout:
//         slot(kk,q,r) @ byte kk*1024 + q*256 + ((r^(kk&7))<<4)
//       -> ds_read_b128 frag reads are conflict-free (uniform XOR per kk),
//          ds_write side spreads evenly (4-way max);
//     - __syncthreads(); 32 x (ds_read_b128 + MFMA 16x16x32), 4 acc chains;
//     - tanh -> per-wave LDS transpose -> one 8-B sc0sc1 store per lane;
//     - __syncthreads() (drains vmcnt per-wave) -> thread0 stores WG flag.
//   Serialized L3 RTs per step: drain + flag + detect + coop-load = 4
//   (old structure: ~6 with 8x the contention).
//   h ring depth 4; flags >= t-1 before reading slot (t-2)&3 keeps the
//   slot-reuse safety argument.  Flags zeroed by init_k.
// Phase 3: fp32 logits GEMV (reads ring slot 3 == h[T]).
// ---------------------------------------------------------------------------

typedef __bf16 bf16x8 __attribute__((ext_vector_type(8)));
typedef float  f32x4  __attribute__((ext_vector_type(4)));
typedef int    i32x4  __attribute__((ext_vector_type(4)));
typedef unsigned long long u64;
typedef unsigned short u16;

#define B_SZ 64
#define T_SZ 512
#define IDIM 512
#define HDIM 1024
#define NCLS 1000
#define MTOT (B_SZ * T_SZ)   // 32768

__device__ __forceinline__ float tanh_fast(float v) {
    float e = __builtin_amdgcn_exp2f(v * 2.885390081777927f);
    return 1.f - 2.f * __builtin_amdgcn_rcpf(e + 1.f);
}

__device__ __forceinline__ bf16x8 cvt8(float4 a, float4 b) {
    bf16x8 v;
    v[0]=(__bf16)a.x; v[1]=(__bf16)a.y; v[2]=(__bf16)a.z; v[3]=(__bf16)a.w;
    v[4]=(__bf16)b.x; v[5]=(__bf16)b.y; v[6]=(__bf16)b.z; v[7]=(__bf16)b.w;
    return v;
}

// MFMA 16x16x32 bf16 layouts (m89/m91 verified):
//   A[m = lane&15][k = (lane>>4)*8 + j]
//   B[k = (lane>>4)*8 + j][n = lane&15]
//   D[row = (lane>>4)*4 + r][col = lane&15]

// ---------------------------------------------------------------------------
// Phase 1: xh GEMM with transposed output (unchanged, proven).
// ---------------------------------------------------------------------------
__global__ __launch_bounds__(256)
void xh_gemm(const float* __restrict__ x,    // (32768, 512)
             const float* __restrict__ Wx,   // (1024, 512)
             const float* __restrict__ bx,   // (1024)
             __bf16* __restrict__ xh_T)      // (1024, 32768) bf16
{
    __shared__ __attribute__((aligned(16))) u16 tile_sh[64 * 72];  // [n][m], stride 72

    const int m0   = (blockIdx.x >> 4) * 64;
    const int n0   = (blockIdx.x & 15) * 64;
    const int wv   = threadIdx.x >> 6;
    const int lane = threadIdx.x & 63;
    const int l15  = lane & 15;
    const int quad = lane >> 4;
    const int nabs = n0 + wv * 16 + l15;

    bf16x8 wxf[16];
#pragma unroll
    for (int kk = 0; kk < 16; ++kk) {
        const float4* p = (const float4*)(Wx + (size_t)nabs * IDIM + kk * 32 + quad * 8);
        wxf[kk] = cvt8(p[0], p[1]);
    }
    const float bxv = bx[nabs];

    f32x4 acc[4] = {{0,0,0,0},{0,0,0,0},{0,0,0,0},{0,0,0,0}};
#pragma unroll
    for (int kk = 0; kk < 16; ++kk) {
#pragma unroll
        for (int rf = 0; rf < 4; ++rf) {
            const float4* p = (const float4*)(x + (size_t)(m0 + rf * 16 + l15) * IDIM + kk * 32 + quad * 8);
            bf16x8 a = cvt8(p[0], p[1]);
            acc[rf] = __builtin_amdgcn_mfma_f32_16x16x32_bf16(a, wxf[kk], acc[rf], 0, 0, 0);
        }
    }
#pragma unroll
    for (int rf = 0; rf < 4; ++rf)
#pragma unroll
        for (int r = 0; r < 4; ++r) {
            __bf16 hv = (__bf16)(acc[rf][r] + bxv);
            tile_sh[(wv * 16 + l15) * 72 + rf * 16 + quad * 4 + r] =
                __builtin_bit_cast(u16, hv);
        }
    __syncthreads();
#pragma unroll
    for (int rep = 0; rep < 2; ++rep) {
        const int nl  = (threadIdx.x >> 3) + rep * 32;
        const int mch = threadIdx.x & 7;
        uint4 v;
        __builtin_memcpy(&v, &tile_sh[nl * 72 + mch * 8], 16);
        *(uint4*)(xh_T + (size_t)(n0 + nl) * MTOT + m0 + mch * 8) = v;
    }
}

// ---------------------------------------------------------------------------
// init: zero sync state.  Layout (ints): flags g*16+v for g=0..3,v=0..7.
// ---------------------------------------------------------------------------
__global__ __launch_bounds__(256)
void init_k(int* sync) {
    sync[threadIdx.x] = 0;
}

#define SB0 __builtin_amdgcn_sched_barrier(0)

// ---------------------------------------------------------------------------
// Phase 2: cooperative-WG ring.
//   h_ring layout: [ring g][slot 0..3][row 0..15][col 0..1023] bf16.
//   grid 32 x 512:  g = blockIdx.x>>3, v = blockIdx.x&7, wave u = tid>>6.
// ---------------------------------------------------------------------------
template <bool HAS_XH>
__global__ __launch_bounds__(512, 2)
void rnn_ring(const float* __restrict__ x,    // (64,512,512)
              const float* __restrict__ Wx,   // (1024,512)
              const float* __restrict__ bx,   // (1024)
              const float* __restrict__ Wh,   // (1024,1024)
              const __bf16* __restrict__ xh,  // (1024,32768) bf16 xh_T (HAS_XH)
              __bf16* h_ring,                 // (4,4,16,1024) bf16, ws
              int* sync)                      // flags, ws
{
    // per-thread xh stash: [tid][r][p] (stride 68 u16 -> 2-way bank, free)
    __shared__ __attribute__((aligned(16))) u16 xh_sh[512 * 68];   // 69632 B
    // h(t-1) staged A-frag-major + XOR swizzle.  32 KB.
    __shared__ __attribute__((aligned(16))) u16 hbuf[16 * 1024];
    // epilogue transpose, per-wave 16x20 region.  5120 B.
    __shared__ __attribute__((aligned(16))) u16 ep_sh[8 * 16 * 20];

    const int tid  = threadIdx.x;
    const int u    = tid >> 6;            // wave in WG
    const int lane = tid & 63;
    const int g    = blockIdx.x >> 3;     // ring (batch rows g*16..+15)
    const int v    = blockIdx.x & 7;      // WG in ring (cols v*128..+127)
    const int w    = v * 8 + u;           // global wave-col index
    const int l15  = lane & 15;
    const int quad = lane >> 4;
    const int nabs = w * 16 + l15;

    bf16x8 whf[32];
#pragma unroll
    for (int kk = 0; kk < 32; ++kk) {
        const float4* p = (const float4*)(Wh + (size_t)nabs * HDIM + kk * 32 + quad * 8);
        whf[kk] = cvt8(p[0], p[1]);
    }
    bf16x8 wxf[16];
    float bxv = 0.f;
    if (!HAS_XH) {
#pragma unroll
        for (int kk = 0; kk < 16; ++kk) {
            const float4* p = (const float4*)(Wx + (size_t)nabs * IDIM + kk * 32 + quad * 8);
            wxf[kk] = cvt8(p[0], p[1]);
        }
        bxv = bx[nabs];
    }

    int* fl           = sync + g * 16;            // one 64B line per ring
    int* myflag       = fl + v;
    const int* pollp  = fl + (lane & 7);
    __bf16* ring      = h_ring + (size_t)g * (4 * 16 * HDIM);
    const float* xrow = x + (size_t)(g * 16 + l15) * T_SZ * IDIM + quad * 8;
    const int prow = lane >> 2;           // epilogue read row
    const int pcg  = lane & 3;            // epilogue read col-group
    const int cr   = 2 * u + (lane >> 5); // coop-load: row this lane fetches
    const int cc   = lane & 31;           // coop-load: 64B col-chunk
    u16* eb = ep_sh + u * 320;

    for (int t = 1; t <= T_SZ; ++t) {
        f32x4 acc0 = {0.f,0.f,0.f,0.f};
        f32x4 acc1 = {0.f,0.f,0.f,0.f};
        f32x4 acc2 = {0.f,0.f,0.f,0.f};
        f32x4 acc3 = {0.f,0.f,0.f,0.f};
        float xhv[4];

        if (HAS_XH) {
            // ---- bulk 16-step xh prefetch (amortized HBM RT) ---------------
            if (((t - 1) & 15) == 0) {
                const int tb = t - 1;
#pragma unroll
                for (int r = 0; r < 4; ++r) {
                    const int row = g * 16 + quad * 4 + r;
                    const uint4* xp = (const uint4*)(xh + (size_t)nabs * MTOT + row * T_SZ + tb);
                    uint4 v0 = xp[0], v1 = xp[1];
                    __builtin_memcpy(&xh_sh[tid * 68 + r * 16],     &v0, 16);
                    __builtin_memcpy(&xh_sh[tid * 68 + r * 16 + 8], &v1, 16);
                }
            }
            const int p = (t - 1) & 15;
#pragma unroll
            for (int r = 0; r < 4; ++r) {
                u16 us = xh_sh[tid * 68 + r * 16 + p];
                xhv[r] = (float)__builtin_bit_cast(__bf16, us);
            }
        } else {
            const float4* xp = (const float4*)(xrow + (size_t)(t - 1) * IDIM);
#pragma unroll
            for (int kk = 0; kk < 16; kk += 2) {
                bf16x8 v0 = cvt8(xp[kk * 8], xp[kk * 8 + 1]);
                acc0 = __builtin_amdgcn_mfma_f32_16x16x32_bf16(v0, wxf[kk], acc0, 0, 0, 0);
                bf16x8 v1 = cvt8(xp[kk * 8 + 8], xp[kk * 8 + 9]);
                acc1 = __builtin_amdgcn_mfma_f32_16x16x32_bf16(v1, wxf[kk + 1], acc1, 0, 0, 0);
            }
#pragma unroll
            for (int r = 0; r < 4; ++r) xhv[r] = bxv;
        }

        if (t > 1) {
            // ---- poll 8 per-WG flags (one L3 line, agent-scope encoding) ---
            int fv;
            do {
                asm volatile("global_load_dword %0, %1, off sc0 sc1\n\ts_waitcnt vmcnt(0)"
                             : "=v"(fv) : "v"(pollp) : "memory");
            } while (!__all(fv >= t - 1));
            SB0;

            // ---- cooperative load: 8 waves fetch 32KB ONCE (4KB/wave) ------
            const __bf16* src = ring + (size_t)(((t - 2) & 3) * 16 + cr) * HDIM + cc * 32;
            i32x4 q0, q1, q2, q3;
            asm volatile("global_load_dwordx4 %0, %4, off sc0 sc1\n\t"
                         "global_load_dwordx4 %1, %4, off offset:16 sc0 sc1\n\t"
                         "global_load_dwordx4 %2, %4, off offset:32 sc0 sc1\n\t"
                         "global_load_dwordx4 %3, %4, off offset:48 sc0 sc1\n\t"
                         "s_waitcnt vmcnt(0)"
                         : "=v"(q0), "=v"(q1), "=v"(q2), "=v"(q3)
                         : "v"(src) : "memory");
            SB0;

            // ---- stage A-frag-major: slot(kk=cc, q, r=cr), XOR swizzle -----
            char* wb = (char*)hbuf + cc * 1024 + ((cr ^ (cc & 7)) << 4);
            *(uint4*)(wb + 0)   = __builtin_bit_cast(uint4, q0);
            *(uint4*)(wb + 256) = __builtin_bit_cast(uint4, q1);
            *(uint4*)(wb + 512) = __builtin_bit_cast(uint4, q2);
            *(uint4*)(wb + 768) = __builtin_bit_cast(uint4, q3);
            __syncthreads();

            // ---- 32 x (ds_read_b128 frag + MFMA), 4 acc chains -------------
#pragma unroll
            for (int kk = 0; kk < 32; kk += 4) {
                uint4 f0, f1, f2, f3;
                __builtin_memcpy(&f0, (const char*)hbuf + (kk+0) * 1024 + quad * 256 + ((l15 ^ ((kk+0) & 7)) << 4), 16);
                __builtin_memcpy(&f1, (const char*)hbuf + (kk+1) * 1024 + quad * 256 + ((l15 ^ ((kk+1) & 7)) << 4), 16);
                __builtin_memcpy(&f2, (const char*)hbuf + (kk+2) * 1024 + quad * 256 + ((l15 ^ ((kk+2) & 7)) << 4), 16);
                __builtin_memcpy(&f3, (const char*)hbuf + (kk+3) * 1024 + quad * 256 + ((l15 ^ ((kk+3) & 7)) << 4), 16);
                acc0 = __builtin_amdgcn_mfma_f32_16x16x32_bf16(__builtin_bit_cast(bf16x8, f0), whf[kk+0], acc0, 0, 0, 0);
                acc1 = __builtin_amdgcn_mfma_f32_16x16x32_bf16(__builtin_bit_cast(bf16x8, f1), whf[kk+1], acc1, 0, 0, 0);
                acc2 = __builtin_amdgcn_mfma_f32_16x16x32_bf16(__builtin_bit_cast(bf16x8, f2), whf[kk+2], acc2, 0, 0, 0);
                acc3 = __builtin_amdgcn_mfma_f32_16x16x32_bf16(__builtin_bit_cast(bf16x8, f3), whf[kk+3], acc3, 0, 0, 0);
            }
        }

        // ---- epilogue: tanh -> per-wave LDS transpose -> one 8-B store -----
#pragma unroll
        for (int r = 0; r < 4; ++r) {
            float a = acc0[r] + acc1[r] + acc2[r] + acc3[r] + xhv[r];
            __bf16 hb = (__bf16)tanh_fast(a);
            eb[(quad * 4 + r) * 20 + l15] = __builtin_bit_cast(u16, hb);
        }
        u64 pv;
        __builtin_memcpy(&pv, &eb[prow * 20 + pcg * 4], 8);   // same-wave, alias-visible
        __bf16* dst = ring + (size_t)(((t - 1) & 3) * 16 + prow) * HDIM + w * 16 + pcg * 4;
        asm volatile("global_store_dwordx2 %0, %1, off sc0 sc1" :: "v"(dst), "v"(pv) : "memory");

        // ---- publish: syncthreads drains all waves' stores, then WG flag ---
        __syncthreads();
        if (tid == 0)
            asm volatile("global_store_dword %0, %1, off sc0 sc1" :: "v"(myflag), "v"(t) : "memory");
    }
}

// ---------------------------------------------------------------------------
// Phase 3: logits[b][j] = sum_k hT[b][k] * Wy[j][k] + by[j]   (fp32)
//   hT row b lives at ring (b>>4), slot 3 (= (T-1)&3), local row (b&15).
// ---------------------------------------------------------------------------
__global__ __launch_bounds__(256)
void logits_k(const __bf16* __restrict__ h_ring, // (4,4,16,1024) bf16
              const float* __restrict__ Wy,      // (1000,1024)
              const float* __restrict__ by,      // (1000)
              float* __restrict__ out)           // (64,1000)
{
    const int j = blockIdx.x;
    const int q = threadIdx.x & 3;
    const int b = threadIdx.x >> 2;
    const float*  wr = Wy + (size_t)j * HDIM + q * 256;
    const __bf16* hr = h_ring + ((size_t)((b >> 4) * 4 + 3) * 16 + (b & 15)) * HDIM + q * 256;
    float s = 0.f;
#pragma unroll 8
    for (int kk = 0; kk < 32; ++kk) {
        bf16x8 h8 = *(const bf16x8*)(hr + kk * 8);
        float4 w0 = *(const float4*)(wr + kk * 8);
        float4 w1 = *(const float4*)(wr + kk * 8 + 4);
        s += w0.x * (float)h8[0] + w0.y * (float)h8[1] + w0.z * (float)h8[2] + w0.w * (float)h8[3]
           + w1.x * (float)h8[4] + w1.y * (float)h8[5] + w1.z * (float)h8[6] + w1.w * (float)h8[7];
    }
    s += __shfl_xor(s, 1);
    s += __shfl_xor(s, 2);
    if (q == 0) out[b * NCLS + j] = s + by[j];
}

extern "C" void kernel_launch(void* const* d_in, const int* in_sizes, int n_in,
                              void* d_out, int out_size, void* d_ws, size_t ws_size,
                              hipStream_t stream) {
    (void)in_sizes; (void)n_in; (void)out_size;
    const float* x  = (const float*)d_in[0];
    const float* Wx = (const float*)d_in[1];
    const float* bx = (const float*)d_in[2];
    const float* Wh = (const float*)d_in[3];
    const float* Wy = (const float*)d_in[4];
    const float* by = (const float*)d_in[5];

    const size_t xh_bytes    = (size_t)MTOT * HDIM * 2;              // 67.1 MB
    const size_t hring_bytes = (size_t)4 * 4 * 16 * HDIM * 2;        // 512 KB
    const size_t sync_bytes  = 256 * sizeof(int);                    // 1 KB
    const bool   big_ws      = ws_size >= xh_bytes + hring_bytes + sync_bytes + 4096;

    if (big_ws) {
        __bf16* xh_T   = (__bf16*)d_ws;
        __bf16* h_ring = (__bf16*)((char*)d_ws + xh_bytes);
        int*    sync   = (int*)((char*)d_ws + xh_bytes + hring_bytes);
        xh_gemm<<<dim3(8192), dim3(256), 0, stream>>>(x, Wx, bx, xh_T);
        init_k<<<dim3(1), dim3(256), 0, stream>>>(sync);
        rnn_ring<true><<<dim3(32), dim3(512), 0, stream>>>(x, Wx, bx, Wh, xh_T, h_ring, sync);
        logits_k<<<dim3(NCLS), dim3(256), 0, stream>>>(h_ring, Wy, by, (float*)d_out);
    } else {
        __bf16* h_ring = (__bf16*)d_ws;
        int*    sync   = (int*)((char*)d_ws + hring_bytes);
        init_k<<<dim3(1), dim3(256), 0, stream>>>(sync);
        rnn_ring<false><<<dim3(32), dim3(512), 0, stream>>>(x, Wx, bx, Wh, nullptr, h_ring, sync);
        logits_k<<<dim3(NCLS), dim3(256), 0, stream>>>(h_ring, Wy, by, (float*)d_out);
    }
}